// Round 1
// baseline (323.530 us; speedup 1.0000x reference)
//
#include <hip/hip_runtime.h>
#include <hip/hip_bf16.h>

typedef __attribute__((ext_vector_type(8))) short bf16x8_t;
typedef __attribute__((ext_vector_type(4))) float f32x4_t;

#define XP_BYTES 55115776u   // 4*16*58*58*128*2
#define WT_BYTES 4718592u    // 4*512*1152*2

typedef __attribute__((address_space(1))) const unsigned int ga_u32_t;
typedef __attribute__((address_space(3))) unsigned int lds_u32_t;

__device__ __forceinline__ void g2l16(const void* g, void* l) {
  __builtin_amdgcn_global_load_lds((ga_u32_t*)g, (lds_u32_t*)l, 16, 0, 0);
}

// ---------------------------------------------------------------------------
// prep_x: x (16,256,56,56) f32  ->  xp (4,16,58,58,128) bf16, inner = hl*64+c
// borders (y=0,57, x=0,57) are zeroed by hipMemsetAsync before this kernel.
// ---------------------------------------------------------------------------
__global__ __launch_bounds__(256) void prep_x(const float* __restrict__ x,
                                              __hip_bfloat16* __restrict__ xp) {
  __shared__ float ls[64 * 57];
  int blk = blockIdx.x;            // (g, b, h) : 4*16*56 = 3584
  int g = blk / 896;
  int r = blk - g * 896;
  int b = r / 56;
  int h = r - b * 56;
  int tid = threadIdx.x;
  const float* src = x + (size_t)(b * 256 + g * 64) * 3136 + h * 56;
  for (int i = tid; i < 64 * 56; i += 256) {
    int c = i / 56, w = i - c * 56;
    ls[c * 57 + w] = src[(size_t)c * 3136 + w];
  }
  __syncthreads();
  __hip_bfloat16* dst = xp + ((size_t)((g * 16 + b) * 58 + h + 1) * 58 + 1) * 128;
  int wp = tid >> 7;               // 0..1
  int inner = tid & 127;
  int hl = inner >> 6, c = inner & 63;
  for (int w0 = 0; w0 < 56; w0 += 2) {
    int w = w0 + wp;
    float v = ls[c * 57 + w];
    __hip_bfloat16 hi = __float2bfloat16(v);
    __hip_bfloat16 val = hl ? __float2bfloat16(v - __bfloat162float(hi)) : hi;
    dst[(size_t)w * 128 + inner] = val;
  }
}

// ---------------------------------------------------------------------------
// prep_w: weight (256,256,3,3) f32 -> wt[g][nb][n=2*ocl+sign][k=tap*128+hl*64+c]
// integer quant levels 0..3 stored as bf16 (exact), duplicated for hl=0/1.
// ---------------------------------------------------------------------------
__global__ __launch_bounds__(256) void prep_w(const float* __restrict__ wgt,
                                              const float* __restrict__ wsc,
                                              __hip_bfloat16* __restrict__ wt) {
  int idx = blockIdx.x * 256 + threadIdx.x;   // 256*256*9 = 589824
  if (idx >= 589824) return;
  int oc = idx / 2304;
  int r = idx - oc * 2304;
  int C = r / 9;
  int tap = r - C * 9;
  int g = C >> 6, c = C & 63;
  float s = wsc[g];
  float rv = wgt[idx] / s;
  float ip = rintf(fminf(fmaxf(rv, 0.f), 3.f));
  float iN = rintf(fminf(fmaxf(-rv, 0.f), 3.f));
  int nb = oc >> 6, ocl = oc & 63;
  size_t base = ((size_t)((g * 4 + nb) * 128 + 2 * ocl)) * 1152 + tap * 128 + c;
  __hip_bfloat16 vp = __float2bfloat16(ip);
  __hip_bfloat16 vn = __float2bfloat16(iN);
  wt[base] = vp;
  wt[base + 64] = vp;
  wt[base + 1152] = vn;
  wt[base + 1152 + 64] = vn;
}

// ---------------------------------------------------------------------------
// Main implicit-GEMM conv. Block tile M=128 (spatial), N=128 (64 oc x 2 signs),
// K-step 64, 18 steps/group, 4 groups. 4 waves (2x2), wave tile 64x64.
// ---------------------------------------------------------------------------
__global__ __launch_bounds__(256, 2) void conv_mfma(
    const unsigned short* __restrict__ xp, const unsigned short* __restrict__ wt,
    const float* __restrict__ wsc, const float* __restrict__ psp,
    const float* __restrict__ psn, float* __restrict__ out) {
  __shared__ unsigned short As[2][128 * 64];
  __shared__ unsigned short Bs[2][128 * 64];

  const int bid = blockIdx.x;
  const int cpx = gridDim.x >> 3;                 // 1568/8 = 196, exact
  const int wg = (bid & 7) * cpx + (bid >> 3);    // bijective XCD swizzle
  const int mblk = wg >> 2;                       // 392 M-tiles
  const int nb = wg & 3;                          // 4 N-tiles

  const int tid = threadIdx.x;
  const int wv = tid >> 6;
  const int l = tid & 63;
  const int wr = wv >> 1, wc = wv & 1;

  const unsigned int ch16 = (unsigned)(((l & 7) ^ (l >> 3)) << 4);  // swizzled src chunk

  unsigned int aoff[4], boff[4];
#pragma unroll
  for (int i = 0; i < 4; ++i) {
    int m = mblk * 128 + wv * 32 + i * 8 + (l >> 3);
    int b = m / 3136;
    int hw = m - b * 3136;
    int h = hw / 56;
    int w = hw - h * 56;
    aoff[i] = (unsigned)((b * 3364 + h * 58 + w) * 256) + ch16;
    int n = nb * 128 + wv * 32 + i * 8 + (l >> 3);
    boff[i] = (unsigned)(n * 2304) + ch16;
  }

  f32x4_t acc[4][4], oacc[4][4];
  const f32x4_t fz = {0.f, 0.f, 0.f, 0.f};
#pragma unroll
  for (int i = 0; i < 4; ++i)
#pragma unroll
    for (int j = 0; j < 4; ++j) { acc[i][j] = fz; oacc[i][j] = fz; }

  const char* xg = (const char*)xp;
  const char* wgp = (const char*)wt;
  char* lA0 = (char*)&As[0][0] + wv * 4096;
  char* lB0 = (char*)&Bs[0][0] + wv * 4096;
  char* lA1 = (char*)&As[1][0] + wv * 4096;
  char* lB1 = (char*)&Bs[1][0] + wv * 4096;

#define STAGE(buf, t)                                                         \
  {                                                                           \
    int g_ = (t) / 18, s_ = (t) - g_ * 18;                                    \
    int tap_ = s_ >> 1, hl_ = s_ & 1;                                         \
    unsigned at_ = (unsigned)(g_ * 13778944) +                                \
                   (unsigned)(((tap_ / 3) * 58 + (tap_ % 3)) << 8) +          \
                   (unsigned)(hl_ << 7);                                      \
    unsigned bt_ = (unsigned)(g_ * 1179648) + ((unsigned)s_ << 7);            \
    char* lA = (buf) ? lA1 : lA0;                                             \
    char* lB = (buf) ? lB1 : lB0;                                             \
    _Pragma("unroll")                                                         \
    for (int i_ = 0; i_ < 4; ++i_) {                                          \
      g2l16(xg + aoff[i_] + at_, lA + i_ * 1024);                             \
      g2l16(wgp + boff[i_] + bt_, lB + i_ * 1024);                            \
    }                                                                         \
  }

  STAGE(0, 0);

  for (int t = 0; t < 72; ++t) {
    __syncthreads();                       // drains vmcnt: stage(t) complete
    if (t + 1 < 72) { STAGE((t + 1) & 1, t + 1); }
    const char* Ab = (const char*)&As[t & 1][0];
    const char* Bb = (const char*)&Bs[t & 1][0];
#pragma unroll
    for (int kk = 0; kk < 2; ++kk) {
      bf16x8_t af[4], bf[4];
      unsigned cidx = (unsigned)(((kk * 4 + (l >> 4)) ^ (l & 7)) << 4);
#pragma unroll
      for (int i = 0; i < 4; ++i) {
        af[i] = *(const bf16x8_t*)(Ab + (wr * 64 + i * 16 + (l & 15)) * 128 + cidx);
        bf[i] = *(const bf16x8_t*)(Bb + (wc * 64 + i * 16 + (l & 15)) * 128 + cidx);
      }
#pragma unroll
      for (int mi = 0; mi < 4; ++mi)
#pragma unroll
        for (int ni = 0; ni < 4; ++ni)
          acc[mi][ni] = __builtin_amdgcn_mfma_f32_16x16x32_bf16(af[mi], bf[ni], acc[mi][ni], 0, 0, 0);
    }
    if ((t % 18) == 17) {                  // end of group: quantize psums
      int gg = t / 18;
      float sw = wsc[gg];
      float smine = (l & 1) ? psn[gg] : psp[gg];
      float rs = sw / smine;               // acc*rs = psum/s
#pragma unroll
      for (int mi = 0; mi < 4; ++mi)
#pragma unroll
        for (int ni = 0; ni < 4; ++ni)
#pragma unroll
          for (int j = 0; j < 4; ++j) {
            float v = acc[mi][ni][j] * rs;
            v = fminf(fmaxf(v, -128.f), 127.f);
            v = rintf(v) * smine;
            float o = __shfl_xor(v, 1);    // partner sign's quantized value
            oacc[mi][ni][j] += (l & 1) ? (o - v) : (v - o);
            acc[mi][ni][j] = 0.f;
          }
    }
  }

  // write: even lanes hold (p - n) for oc = nb*64 + col/2
  if (!(l & 1)) {
#pragma unroll
    for (int ni = 0; ni < 4; ++ni) {
      int col = wc * 64 + ni * 16 + (l & 15);
      int oc = nb * 64 + (col >> 1);
#pragma unroll
      for (int mi = 0; mi < 4; ++mi) {
        int m0 = mblk * 128 + wr * 64 + mi * 16 + ((l >> 4) << 2);
#pragma unroll
        for (int j = 0; j < 4; ++j) {
          int m = m0 + j;
          int b = m / 3136;
          int hw = m - b * 3136;
          out[(size_t)((b << 8) + oc) * 3136 + hw] = oacc[mi][ni][j];
        }
      }
    }
  }
#undef STAGE
}

// ---------------------------------------------------------------------------
// Fallback (ws too small): direct conv with inline weight quantization.
// ---------------------------------------------------------------------------
__global__ __launch_bounds__(256) void naive_conv(
    const float* __restrict__ x, const float* __restrict__ wgt,
    const float* __restrict__ wsc, const float* __restrict__ psp,
    const float* __restrict__ psn, float* __restrict__ out) {
  int idx = blockIdx.x * 256 + threadIdx.x;
  if (idx >= 12845056) return;
  int b = idx / 802816;
  int r = idx - b * 802816;
  int oc = r / 3136;
  int hw = r - oc * 3136;
  int h = hw / 56, w = hw - (hw / 56) * 56;
  float o = 0.f;
  for (int g = 0; g < 4; ++g) {
    float sw = wsc[g];
    float inv = 1.f / sw;
    float pp = 0.f, pn = 0.f;
    for (int tap = 0; tap < 9; ++tap) {
      int y = h + tap / 3 - 1, xx = w + tap % 3 - 1;
      if (y < 0 || y > 55 || xx < 0 || xx > 55) continue;
      const float* xr = x + (size_t)(b * 256 + g * 64) * 3136 + y * 56 + xx;
      const float* wrr = wgt + (size_t)oc * 2304 + (size_t)(g * 64) * 9 + tap;
      for (int c = 0; c < 64; ++c) {
        float xv = xr[(size_t)c * 3136];
        float rv = wrr[c * 9] * inv;
        pp += xv * rintf(fminf(fmaxf(rv, 0.f), 3.f));
        pn += xv * rintf(fminf(fmaxf(-rv, 0.f), 3.f));
      }
    }
    float sp = psp[g], sn = psn[g];
    o += rintf(fminf(fmaxf(pp * (sw / sp), -128.f), 127.f)) * sp;
    o -= rintf(fminf(fmaxf(pn * (sw / sn), -128.f), 127.f)) * sn;
  }
  out[idx] = o;
}

extern "C" void kernel_launch(void* const* d_in, const int* in_sizes, int n_in,
                              void* d_out, int out_size, void* d_ws, size_t ws_size,
                              hipStream_t stream) {
  const float* x = (const float*)d_in[0];
  const float* wgt = (const float*)d_in[1];
  const float* wsc = (const float*)d_in[2];
  const float* psp = (const float*)d_in[3];
  const float* psn = (const float*)d_in[4];
  float* out = (float*)d_out;

  if (ws_size >= (size_t)XP_BYTES + (size_t)WT_BYTES) {
    unsigned short* xpw = (unsigned short*)d_ws;
    unsigned short* wtw = (unsigned short*)((char*)d_ws + XP_BYTES);
    hipMemsetAsync(d_ws, 0, XP_BYTES, stream);
    prep_x<<<3584, 256, 0, stream>>>(x, (__hip_bfloat16*)xpw);
    prep_w<<<2304, 256, 0, stream>>>(wgt, wsc, (__hip_bfloat16*)wtw);
    conv_mfma<<<1568, 256, 0, stream>>>(xpw, wtw, wsc, psp, psn, out);
  } else {
    naive_conv<<<(12845056 + 255) / 256, 256, 0, stream>>>(x, wgt, wsc, psp, psn, out);
  }
}